// Round 2
// baseline (127.567 us; speedup 1.0000x reference)
//
#include <hip/hip_runtime.h>

#define EPS 1e-5f

typedef float v2f __attribute__((ext_vector_type(2)));

constexpr int B = 32;
constexpr int H = 512;
constexpr int W = 512;
constexpr int NPIX = H * W;          // 262144
constexpr int P = 13;
constexpr int HP = H - P + 1;        // 500
constexpr int WP = W - P + 1;        // 500
constexpr int TILES_X = 8;           // 64 output cols per tile, 1 per lane
constexpr int BAND_OUT = 40;         // output rows per band
constexpr int BANDS_Y = 13;          // bands 0..11 -> rows 0..479; band 12 (y0=460) -> 480..499
constexpr int G = 13;                // rows per staged group == ring depth
constexpr int NGROUPS = 4;           // 52 input rows; 460+52=512 exactly -> no row clamp
constexpr int ITER_LAST_OWN = 20;    // band 12 owns rows 480..511 -> t >= 20
constexpr int ITER_LAST_EMIT = 32;   // band 12 emits rows 480..499 -> t >= 32
constexpr int BLOCKS_PER_B = TILES_X * BANDS_Y;  // 104
constexpr int RS = 76;               // LDS row stride: 64 cols + 12 halo = 76 = 19 lanes x 16B DMA

// direct global->LDS DMA, 16 B per active lane, dst = uniform base + lane*16
#define GLOAD_LDS16(gp, lp)                                                    \
  __builtin_amdgcn_global_load_lds(                                            \
      (const __attribute__((address_space(1))) unsigned int*)(const void*)(gp),\
      (__attribute__((address_space(3))) unsigned int*)(void*)(lp), 16, 0, 0)

// ---------------------------------------------------------------------------
// R8 = R7 resubmit (R7 bench was an infra failure: "container failed twice",
// no counters). Audit found no hang/OOB/numerics risk; same logic as the
// verified 122us baseline with occupancy parameters changed.
//
// R7 occupancy redesign: 1 output col per lane, 64-col tiles.
//  - Evidence (R6 rocprof): Occupancy 10% (0.8 waves/SIMD), VALUBusy 15%,
//    HBM 7% -> latency-bound, nothing co-resident to hide LDS/DMA stalls.
//    Per-step wall ~2000 cyc vs ~250 cyc of issue work.
//  - LDS/wave ~ cols/wave: 64-wide tile halves LDS to 15808 B ->
//    10 blocks/CU (was 5), grid 3328 (13/CU of work) -> cap binds at 10.
//  - Ring halves to 13x5 scalars = 65 VGPR (was 130 as v2f) -> regalloc can
//    pipeline ds_reads across unrolled steps again.
//  - Tap base is lane-unaligned (float tid) -> scalar pair loads; the DS
//    load/store optimizer merges them to ds_read2_b32 (no align constraint):
//    6 read2 + 1 b32 per plane = 14 LDS instr/step, same as R6's b64 count.
//    Tap math stays packed (pk_add/pk_fma over v2f tap pairs).
//  - R6's async global_load_lds double-buffered staging kept verbatim.
//  - group loop dynamic (R3 lesson), no launch_bounds waves cap (R4 lesson).
//    Spill tripwire: WRITE_SIZE.
// grid = 32*8*13 = 3328 single-wave blocks; LDS 15.8 KB -> 10 blocks/CU.
// workspace: 3328*6 floats = 78 KiB.
// ---------------------------------------------------------------------------
__global__ __launch_bounds__(64) void ncc_fused_kernel(
    const float* __restrict__ x1, const float* __restrict__ x2,
    float* __restrict__ part) {
  const int bid = blockIdx.x;
  const int b    = bid / BLOCKS_PER_B;
  const int rem  = bid % BLOCKS_PER_B;
  const int tile = rem % TILES_X;
  const int band = rem / TILES_X;
  const bool last = (band == BANDS_Y - 1);
  const int x0 = tile * 64;
  const int y0 = last ? (HP - BAND_OUT) : band * BAND_OUT;  // 460 for last band
  const int tid = threadIdx.x;
  const int c0 = x0 + tid;
  const bool valid = c0 < WP;

  __shared__ float sa[2][G][RS];   // 7904 B
  __shared__ float sb[2][G][RS];   // 7904 B

  const float* r1 = x1 + (size_t)b * NPIX + (size_t)y0 * W + x0;
  const float* r2 = x2 + (size_t)b * NPIX + (size_t)y0 * W + x0;

  // loader: 19 lanes x float4 = 76 floats/row/plane. Tile 7 clamp: lanes
  // 16..18 re-read cols 508..511 into LDS floats 64..75, consumed only by
  // out-cols >= 500 (masked). DMA dst is lane-indexed: base + lane*16.
  int qoff = tid * 4;
  { int mx = W - x0 - 4; if (qoff > mx) qoff = mx; }
  const bool loader = tid < 19;

  auto stage = [&](int g, int buf) {
    if (loader) {
#pragma unroll
      for (int r = 0; r < G; ++r) {
        GLOAD_LDS16(r1 + (size_t)(g * G + r) * W + qoff, &sa[buf][r][0]);
        GLOAD_LDS16(r2 + (size_t)(g * G + r) * W + qoff, &sb[buf][r][0]);
      }
    }
  };

  // vertical ring in registers, scalar per quantity (1 col per lane)
  float rr1[G], rr2[G], rr11[G], rr22[G], rr12[G];
  float S1 = 0.f, S2 = 0.f, S11 = 0.f, S22 = 0.f, S12 = 0.f;
  float g1 = 0.f, g2 = 0.f, g11 = 0.f, g22 = 0.f, g12 = 0.f;
  float acc = 0.f;
  const float inv_n = 1.0f / 169.0f;

  auto step = [&](int u, int buf, int t, bool fill) {
    const float* pa = &sa[buf][u][tid];
    const float* pb = &sb[buf][u][tid];
    // taps 0..12; pairs (2j,2j+1) j=0..5 merge into ds_read2_b32, tap 12 b32
    v2f A2[6], B2[6];
#pragma unroll
    for (int j = 0; j < 6; ++j) {
      A2[j] = (v2f){pa[2 * j], pa[2 * j + 1]};
      B2[j] = (v2f){pb[2 * j], pb[2 * j + 1]};
    }
    float a12 = pa[12], b12 = pb[12];

    v2f q11 = A2[0] * A2[0], q22 = B2[0] * B2[0], q12 = A2[0] * B2[0];
    v2f h1v = A2[0], h2v = B2[0], h11v = q11, h22v = q22, h12v = q12;
#pragma unroll
    for (int j = 1; j < 6; ++j) {
      h1v += A2[j];
      h2v += B2[j];
      h11v += A2[j] * A2[j];
      h22v += B2[j] * B2[j];
      h12v += A2[j] * B2[j];
    }
    float h1 = h1v.x + h1v.y + a12;
    float h2 = h2v.x + h2v.y + b12;
    float h11 = fmaf(a12, a12, h11v.x + h11v.y);
    float h22 = fmaf(b12, b12, h22v.x + h22v.y);
    float h12 = fmaf(a12, b12, h12v.x + h12v.y);

    // global moments: own col c0 = tap 0; squares reused from q*
    bool owned = last ? (t >= ITER_LAST_OWN) : (t < BAND_OUT);
    if (owned) {
      g1 += A2[0].x; g2 += B2[0].x;
      g11 += q11.x; g22 += q22.x; g12 += q12.x;
    }

    // vertical sliding sums via register ring
    if (fill) {
      S1 += h1; S2 += h2; S11 += h11; S22 += h22; S12 += h12;
    } else {
      S1 += h1 - rr1[u]; S2 += h2 - rr2[u];
      S11 += h11 - rr11[u]; S22 += h22 - rr22[u]; S12 += h12 - rr12[u];
    }
    rr1[u] = h1; rr2[u] = h2; rr11[u] = h11; rr22[u] = h22; rr12[u] = h12;

    // emit output row y0 + t - 12 (band 12 suppresses rows < 480)
    bool do_out = (t >= 12) && (!last || t >= ITER_LAST_EMIT);
    if (do_out) {
      float m1 = S1 * inv_n, m2 = S2 * inv_n;
      float vv1 = fmaf(-m1, m1, S11 * inv_n) + EPS;
      float vv2 = fmaf(-m2, m2, S22 * inv_n) + EPS;
      float cross = fmaf(-m1, S2, S12);
      float cc = cross * rsqrtf(vv1 * vv2);
      acc += valid ? cc : 0.f;
    }
  };

  // prologue: stage group 0, drain, launch async prefetch of group 1
  stage(0, 0);
  __syncthreads();            // drains DMA(0) — only exposed load latency
  stage(1, 1);                // in flight during fill compute

#pragma unroll
  for (int u = 0; u < G; ++u) step(u, 0, u, true);
  __syncthreads();            // drains DMA(1), long since landed

#pragma clang loop unroll(disable)
  for (int g = 1; g < NGROUPS; ++g) {
    if (g + 1 < NGROUPS) stage(g + 1, (g + 1) & 1);  // async into free buffer
    const int buf = g & 1;
#pragma unroll
    for (int u = 0; u < G; ++u) step(u, buf, g * G + u, false);
    __syncthreads();          // drains prefetch issued before this group
  }

  // wave-reduce 6 scalars, lane 0 writes block slot
  float v0 = acc;
  float w1 = g1, w2 = g2, w3 = g11, w4 = g22, w5 = g12;
#pragma unroll
  for (int off = 32; off > 0; off >>= 1) {
    v0 += __shfl_down(v0, off, 64);
    w1 += __shfl_down(w1, off, 64);
    w2 += __shfl_down(w2, off, 64);
    w3 += __shfl_down(w3, off, 64);
    w4 += __shfl_down(w4, off, 64);
    w5 += __shfl_down(w5, off, 64);
  }
  if (tid == 0) {
    float* o = part + (size_t)bid * 6;
    o[0] = v0; o[1] = w1; o[2] = w2; o[3] = w3; o[4] = w4; o[5] = w5;
  }
}

// ---------------------------------------------------------------------------
// Reduce per-block partials; one block per batch.
// out[b] = 0.5*global_ncc + 0.5*patch_sum/(HP*WP*169)
// ---------------------------------------------------------------------------
__global__ __launch_bounds__(64) void final_kernel(
    const float* __restrict__ part, float* __restrict__ out) {
  int b = blockIdx.x;
  int tid = threadIdx.x;
  float s[6] = {0.f, 0.f, 0.f, 0.f, 0.f, 0.f};
  for (int i = tid; i < BLOCKS_PER_B; i += 64) {
    const float* p = part + (size_t)(b * BLOCKS_PER_B + i) * 6;
#pragma unroll
    for (int k = 0; k < 6; ++k) s[k] += p[k];
  }
#pragma unroll
  for (int off = 32; off > 0; off >>= 1) {
#pragma unroll
    for (int k = 0; k < 6; ++k) s[k] += __shfl_down(s[k], off, 64);
  }
  if (tid == 0) {
    float Nf = (float)NPIX;
    float m1 = s[1] / Nf;
    float m2 = s[2] / Nf;
    float v1 = fmaf(-m1, m1, s[3] / Nf);
    float v2 = fmaf(-m2, m2, s[4] / Nf);
    float cross = fmaf(-Nf * m1, m2, s[5]);
    float g = cross * rsqrtf((v1 + EPS) * (v2 + EPS)) / Nf;
    float patch = s[0] / ((float)HP * (float)WP * 169.0f);
    out[b] = 0.5f * g + 0.5f * patch;
  }
}

extern "C" void kernel_launch(void* const* d_in, const int* in_sizes, int n_in,
                              void* d_out, int out_size, void* d_ws, size_t ws_size,
                              hipStream_t stream) {
  const float* x1 = (const float*)d_in[0];
  const float* x2 = (const float*)d_in[1];
  float* out = (float*)d_out;
  float* part = (float*)d_ws;   // 3328 * 6 floats = 78 KiB; every slot written

  ncc_fused_kernel<<<B * BLOCKS_PER_B, 64, 0, stream>>>(x1, x2, part);
  final_kernel<<<B, 64, 0, stream>>>(part, out);
}